// Round 8
// baseline (253.886 us; speedup 1.0000x reference)
//
#include <hip/hip_runtime.h>
#include <stdint.h>

// MultiHeadSelfAttention: B=2, T=2048, C=1024, H=16, Dk=64, fp32 in/out.
// R8: k_attn rewritten BARRIER-FREE. K and V^T are A-operands in the S^T
//     formulation -> their fragments are 16B contiguous global loads
//     (L2-cached), no LDS staging, no DMA, no double buffer. LDS holds only
//     the per-wave P round-trip. Zero __syncthreads in the kernel; waves
//     drift freely and the compiler pipelines VMEM across iterations.
//     XCD swizzle: all 16 q-blocks of one bh share id%8 -> one XCD's L2.

typedef __bf16 bf16;
typedef __bf16 bf16x8 __attribute__((ext_vector_type(8)));
typedef __bf16 bf16x4 __attribute__((ext_vector_type(4)));
typedef float  f32x4  __attribute__((ext_vector_type(4)));

#define SEQ_T 2048
#define CDIM 1024
#define BT   4096   // B*T

// async global->LDS, 16B per lane. LDS dest = wave-uniform base + lane*16.
__device__ __forceinline__ void gload16(const void* g, void* l) {
    __builtin_amdgcn_global_load_lds(
        (const __attribute__((address_space(1))) void*)(uintptr_t)g,
        (__attribute__((address_space(3))) void*)(uint32_t)(uintptr_t)l,
        16, 0, 0);
}

// ---------------------------------------------------------------- convert
__global__ __launch_bounds__(256) void k_convert(
    const float* __restrict__ x, const float* __restrict__ wqkv,
    const float* __restrict__ wout,
    bf16* __restrict__ xb, bf16* __restrict__ wqb, bf16* __restrict__ wob) {
    const int NX = (BT * CDIM) / 4;        // 1048576
    const int NQ = (3 * CDIM * CDIM) / 4;  // 786432
    const int NO = (CDIM * CDIM) / 4;      // 262144
    int i = blockIdx.x * 256 + threadIdx.x;
    const float4* src; bf16* dst; int j;
    if (i < NX)                    { src = (const float4*)x;    dst = xb;  j = i; }
    else if ((j = i - NX) < NQ)    { src = (const float4*)wqkv; dst = wqb; }
    else if ((j = i - NX - NQ) < NO) { src = (const float4*)wout; dst = wob; }
    else return;
    float4 v = src[j];
    bf16x4 o = { (bf16)v.x, (bf16)v.y, (bf16)v.z, (bf16)v.w };
    ((bf16x4*)dst)[j] = o;
}

// ------------------------------------------------------------- GEMM core
// C[BM x BN] = A[m0..][K=1024] * Bw[n0..][K=1024]^T, K-contiguous bf16.
// 4 waves in 2x2; wave tile (MI*16) x (NI*16). Chunk-XOR swizzle: 2-way
// bank aliasing on ds_read_b128 (free, m136).
template <int BM, int BN, int MI, int NI>
__device__ __forceinline__ void gemm_core(
    const bf16* __restrict__ A, const bf16* __restrict__ Bw,
    bf16* As, bf16* Bs, int m0, int n0, int tid, f32x4 (&acc)[MI][NI]) {
    const int lane = tid & 63, wv = tid >> 6;
    const int quad = lane >> 4, lo = lane & 15;
    const int wm = (wv >> 1) * MI * 16, wn = (wv & 1) * NI * 16;
#pragma unroll
    for (int mi = 0; mi < MI; ++mi)
#pragma unroll
        for (int ni = 0; ni < NI; ++ni) acc[mi][ni] = 0.0f;

    for (int kk = 0; kk < 1024; kk += 32) {
        __syncthreads();
#pragma unroll
        for (int c = 0; c < BM / 64; ++c) {
            int slot = c * 256 + tid;
            int row = slot >> 2, sc = slot & 3;
            int g = sc ^ ((row >> 1) & 3);
            gload16(A + (m0 + row) * 1024 + kk + g * 8,
                    As + c * 2048 + (tid & 192) * 8);
        }
#pragma unroll
        for (int c = 0; c < BN / 64; ++c) {
            int slot = c * 256 + tid;
            int row = slot >> 2, sc = slot & 3;
            int g = sc ^ ((row >> 1) & 3);
            gload16(Bw + (n0 + row) * 1024 + kk + g * 8,
                    Bs + c * 2048 + (tid & 192) * 8);
        }
        __syncthreads();
        bf16x8 af[MI], bb[NI];
#pragma unroll
        for (int mi = 0; mi < MI; ++mi) {
            int row = wm + mi * 16 + lo;
            int ch = quad ^ ((row >> 1) & 3);
            af[mi] = *(const bf16x8*)(As + row * 32 + ch * 8);
        }
#pragma unroll
        for (int ni = 0; ni < NI; ++ni) {
            int row = wn + ni * 16 + lo;
            int ch = quad ^ ((row >> 1) & 3);
            bb[ni] = *(const bf16x8*)(Bs + row * 32 + ch * 8);
        }
#pragma unroll
        for (int mi = 0; mi < MI; ++mi)
#pragma unroll
            for (int ni = 0; ni < NI; ++ni)
                acc[mi][ni] = __builtin_amdgcn_mfma_f32_16x16x32_bf16(
                    af[mi], bb[ni], acc[mi][ni], 0, 0, 0);
    }
}

// ------------------------------------------------------------- QKV GEMM
// n in [0,3072): which=n>>10 (uniform per block), h=(n>>6)&15, d=n&63.
// q pre-scaled by log2(e)/8 (softmax runs in exp2 domain).
// Q/K: C-tile transposed through LDS -> coalesced b128 stores to [b,h,t,d].
// V: written transposed to vt[b,h,d,t] via packed b64 (4 consecutive t).
__global__ __launch_bounds__(256) void k_gemm_qkv(
    const bf16* __restrict__ A, const bf16* __restrict__ Bw,
    const float* __restrict__ bias,
    bf16* __restrict__ qb, bf16* __restrict__ kb, bf16* __restrict__ vt) {
    __shared__ __align__(16) char pool[18432];   // As 8K | Bs 8K ; reused as T
    bf16* As = (bf16*)pool;
    bf16* Bs = (bf16*)(pool + 8192);
    bf16* T  = (bf16*)pool;                      // [64 m][128+8 n] = 17408 B
    const int tid = threadIdx.x;
    const int m0 = blockIdx.y * 128, n0 = blockIdx.x * 128;
    f32x4 acc[4][4];
    gemm_core<128, 128, 4, 4>(A, Bw, As, Bs, m0, n0, tid, acc);
    const int lane = tid & 63, wv = tid >> 6;
    const int quad = lane >> 4, lo = lane & 15;
    const int wm = (wv >> 1) * 64, wn = (wv & 1) * 64;
    const int which = n0 >> 10;
    if (which == 2) {  // V: write transposed [b,h,d,t], packed 4x bf16
#pragma unroll
        for (int ni = 0; ni < 4; ++ni) {
            int n = n0 + wn + ni * 16 + lo;
            int h = (n >> 6) & 15, d = n & 63;
            float bv = bias[n];
#pragma unroll
            for (int mi = 0; mi < 4; ++mi) {
                int m = m0 + wm + mi * 16 + quad * 4;   // 4-aligned, +r<4
                int b = m >> 11, t = m & 2047;
                bf16x4 v4;
#pragma unroll
                for (int r = 0; r < 4; ++r) v4[r] = (bf16)(acc[mi][ni][r] + bv);
                *(bf16x4*)(vt + ((size_t)(b * 16 + h) * 64 + d) * 2048 + t) = v4;
            }
        }
    } else {
        bf16* dst = which == 0 ? qb : kb;
        const float scale = which == 0 ? 0.125f * 1.44269504089f : 1.0f;
        // two half-passes over m (64 rows each) through LDS transpose buffer
#pragma unroll
        for (int p = 0; p < 2; ++p) {
            __syncthreads();   // pool safe to reuse / previous pass read done
            if ((wv >> 1) == p) {   // waves holding m-rows [p*64, p*64+64)
#pragma unroll
                for (int ni = 0; ni < 4; ++ni) {
                    int n = wn + ni * 16 + lo;
                    float bv = bias[n0 + n];
#pragma unroll
                    for (int mi = 0; mi < 4; ++mi) {
#pragma unroll
                        for (int r = 0; r < 4; ++r) {
                            int ml = mi * 16 + quad * 4 + r;
                            T[ml * 136 + n] =
                                (bf16)((acc[mi][ni][r] + bv) * scale);
                        }
                    }
                }
            }
            __syncthreads();
            // all 256 threads: 4 chunks each (64 m x 16 n-chunks of 8)
#pragma unroll
            for (int pass = 0; pass < 4; ++pass) {
                int chunk = pass * 256 + tid;
                int ml = chunk >> 4, nc = chunk & 15;
                bf16x8 v = *(const bf16x8*)(T + ml * 136 + nc * 8);
                int n_g = n0 + nc * 8;
                int h = (n_g >> 6) & 15, d = n_g & 63;
                int t = m0 + p * 64 + ml;
                int b = t >> 11, tt = t & 2047;
                *(bf16x8*)(dst + ((size_t)(b * 16 + h) * 2048 + tt) * 64 + d) = v;
            }
        }
    }
}

// ------------------------------------------------------------ out-proj GEMM
// 128x64 tiles -> 512 blocks (2/CU).
__global__ __launch_bounds__(256) void k_gemm_out(
    const bf16* __restrict__ A, const bf16* __restrict__ Bw,
    const float* __restrict__ bias, float* __restrict__ out) {
    __shared__ __align__(16) bf16 As[128 * 32];
    __shared__ __align__(16) bf16 Bs[64 * 32];
    const int tid = threadIdx.x;
    const int m0 = blockIdx.y * 128, n0 = blockIdx.x * 64;
    f32x4 acc[4][2];
    gemm_core<128, 64, 4, 2>(A, Bw, As, Bs, m0, n0, tid, acc);
    const int lane = tid & 63, wv = tid >> 6;
    const int quad = lane >> 4, lo = lane & 15;
    const int wm = (wv >> 1) * 64, wn = (wv & 1) * 32;
#pragma unroll
    for (int ni = 0; ni < 2; ++ni) {
        int n = n0 + wn + ni * 16 + lo;
        float bv = bias[n];
#pragma unroll
        for (int mi = 0; mi < 4; ++mi) {
#pragma unroll
            for (int r = 0; r < 4; ++r) {
                int m = m0 + wm + mi * 16 + quad * 4 + r;
                out[(size_t)m * 1024 + n] = acc[mi][ni][r] + bv;
            }
        }
    }
}

// ---------------------------------------------------------- flash attention
// R8: barrier-free. S^T = K*Q^T with A=K fragments loaded DIRECTLY from
// global (16B contiguous per lane, L2-cached), B=Q in regs. P^T round-trips
// through per-wave LDS (b64 write / b128 read). O^T = V^T*P^T with A=V^T
// fragments from global. denom = ones*P^T. q-tile 128 (4 waves x 32 q),
// grid 512. LDS = Ps only (18 KB). ZERO __syncthreads.
__global__ __launch_bounds__(256) void k_attn(
    const bf16* __restrict__ qg, const bf16* __restrict__ kg,
    const bf16* __restrict__ vtg, bf16* __restrict__ og) {
    __shared__ __align__(16) bf16 Ps[4][32 * 72];  // per-wave [q][s], +8 pad
    const int tid = threadIdx.x, lane = tid & 63, wv = tid >> 6;
    const int quad = lane >> 4, lo = lane & 15;
    // XCD swizzle: 16 q-blocks of one bh share (id & 7) -> same XCD L2.
    const int id = blockIdx.x;
    const int bh = (id & 7) | (((id >> 3) & 3) << 3);
    const int q0 = (id >> 5) * 128;
    const bf16* Qb = qg + (size_t)bh * 2048 * 64;
    const bf16* Kb = kg + (size_t)bh * 2048 * 64;
    const bf16* Vb = vtg + (size_t)bh * 64 * 2048;
    bf16* PsW = &Ps[wv][0];

    // Q B-fragments: loop-invariant, from global into 16 VGPRs.
    bf16x8 bq[2][2];
#pragma unroll
    for (int nb = 0; nb < 2; ++nb)
#pragma unroll
        for (int ks = 0; ks < 2; ++ks)
            bq[nb][ks] = *(const bf16x8*)(
                Qb + (size_t)(q0 + wv * 32 + nb * 16 + lo) * 64 + ks * 32 + quad * 8);

    bf16x8 ones;
#pragma unroll
    for (int j = 0; j < 8; ++j) ones[j] = (bf16)1.0f;

    f32x4 oaccT[4][2];  // O^T: [d-block][q-block], col=q=lo, row=d=quad*4+r
    f32x4 osum[2];      // denominator, col=q=lo
#pragma unroll
    for (int db = 0; db < 4; ++db)
#pragma unroll
        for (int nb = 0; nb < 2; ++nb) oaccT[db][nb] = 0.0f;
    osum[0] = 0.0f; osum[1] = 0.0f;

    // hoisted per-lane offsets
    int koff[4][2], voff[4][2];
#pragma unroll
    for (int i4 = 0; i4 < 4; ++i4)
#pragma unroll
        for (int k2 = 0; k2 < 2; ++k2) {
            koff[i4][k2] = (i4 * 16 + lo) * 64 + k2 * 32 + quad * 8;
            voff[i4][k2] = (i4 * 16 + lo) * 2048 + k2 * 32 + quad * 8;
        }

    const bf16* Kp = Kb;
    const bf16* Vp = Vb;
    for (int it = 0; it < SEQ_T / 64; ++it) {
        // A-fragments of K straight from global (L2)
        bf16x8 ak[4][2];
#pragma unroll
        for (int sb = 0; sb < 4; ++sb)
#pragma unroll
            for (int ks = 0; ks < 2; ++ks)
                ak[sb][ks] = *(const bf16x8*)(Kp + koff[sb][ks]);

        // S^T = K*Q^T
        f32x4 sacc[4][2];
#pragma unroll
        for (int sb = 0; sb < 4; ++sb)
#pragma unroll
            for (int nb = 0; nb < 2; ++nb) sacc[sb][nb] = 0.0f;
#pragma unroll
        for (int ks = 0; ks < 2; ++ks)
#pragma unroll
            for (int sb = 0; sb < 4; ++sb)
#pragma unroll
                for (int nb = 0; nb < 2; ++nb)
                    sacc[sb][nb] = __builtin_amdgcn_mfma_f32_16x16x32_bf16(
                        ak[sb][ks], bq[nb][ks], sacc[sb][nb], 0, 0, 0);

        // A-fragments of V^T straight from global (L2) — independent of P
        bf16x8 av[4][2];
#pragma unroll
        for (int db = 0; db < 4; ++db)
#pragma unroll
            for (int ks2 = 0; ks2 < 2; ++ks2)
                av[db][ks2] = *(const bf16x8*)(Vp + voff[db][ks2]);

        // P^T = exp2(S^T) -> per-wave LDS [q][s] (pad 72), b64 writes
#pragma unroll
        for (int sb = 0; sb < 4; ++sb)
#pragma unroll
            for (int nb = 0; nb < 2; ++nb) {
                bf16x4 p4;
#pragma unroll
                for (int r = 0; r < 4; ++r) p4[r] = (bf16)exp2f(sacc[sb][nb][r]);
                *(bf16x4*)(PsW + (nb * 16 + lo) * 72 + sb * 16 + quad * 4) = p4;
            }

        // read P^T back as B-operand (b128), same wave -> no barrier
        bf16x8 bp[2][2];
#pragma unroll
        for (int nb = 0; nb < 2; ++nb)
#pragma unroll
            for (int ks2 = 0; ks2 < 2; ++ks2)
                bp[nb][ks2] = *(const bf16x8*)(
                    PsW + (nb * 16 + lo) * 72 + ks2 * 32 + quad * 8);

        // O^T += V^T * P^T ; denom += ones * P^T
#pragma unroll
        for (int ks2 = 0; ks2 < 2; ++ks2) {
#pragma unroll
            for (int nb = 0; nb < 2; ++nb)
                osum[nb] = __builtin_amdgcn_mfma_f32_16x16x32_bf16(
                    ones, bp[nb][ks2], osum[nb], 0, 0, 0);
#pragma unroll
            for (int db = 0; db < 4; ++db)
#pragma unroll
                for (int nb = 0; nb < 2; ++nb)
                    oaccT[db][nb] = __builtin_amdgcn_mfma_f32_16x16x32_bf16(
                        av[db][ks2], bp[nb][ks2], oaccT[db][nb], 0, 0, 0);
        }
        Kp += 64 * 64;
        Vp += 64;
    }

    // epilogue: O^T/denom -> attn_out [b, t, h*64+d]; packed 8B stores.
    const int b = bh >> 4, h = bh & 15;
#pragma unroll
    for (int nb = 0; nb < 2; ++nb) {
        float inv = 1.0f / osum[nb][0];
        int t = q0 + wv * 32 + nb * 16 + lo;
#pragma unroll
        for (int db = 0; db < 4; ++db) {
            bf16x4 o4;
#pragma unroll
            for (int r = 0; r < 4; ++r) o4[r] = (bf16)(oaccT[db][nb][r] * inv);
            *(bf16x4*)(og + ((size_t)b * 2048 + t) * 1024 + h * 64 + db * 16 + quad * 4) = o4;
        }
    }
}

// ---------------------------------------------------------------- launcher
extern "C" void kernel_launch(void* const* d_in, const int* in_sizes, int n_in,
                              void* d_out, int out_size, void* d_ws, size_t ws_size,
                              hipStream_t stream) {
    const float* x     = (const float*)d_in[0];
    const float* qkv_w = (const float*)d_in[1];
    const float* qkv_b = (const float*)d_in[2];
    const float* out_w = (const float*)d_in[3];
    const float* out_b = (const float*)d_in[4];
    float* out = (float*)d_out;
    char* ws = (char*)d_ws;
    // ws layout (48 MB total)
    bf16* xb  = (bf16*)(ws);                       // 8 MB  [4096][1024]
    bf16* wqb = (bf16*)(ws + 8388608);             // 6 MB  [3072][1024]
    bf16* wob = (bf16*)(ws + 14680064);            // 2 MB  [1024][1024]
    bf16* qb  = (bf16*)(ws + 16777216);            // 8 MB  [b,h,t,d]
    bf16* kb  = (bf16*)(ws + 25165824);            // 8 MB  [b,h,t,d]
    bf16* vt  = (bf16*)(ws + 33554432);            // 8 MB  [b,h,d,t]
    bf16* ao  = (bf16*)(ws + 41943040);            // 8 MB  [4096][1024]

    k_convert<<<8192, 256, 0, stream>>>(x, qkv_w, out_w, xb, wqb, wob);
    k_gemm_qkv<<<dim3(24, 32), 256, 0, stream>>>(xb, wqb, qkv_b, qb, kb, vt);
    k_attn<<<512, 256, 0, stream>>>(qb, kb, vt, ao);
    k_gemm_out<<<dim3(16, 32), 256, 0, stream>>>(ao, wob, out_b, out);
}

// Round 9
// 198.191 us; speedup vs baseline: 1.2810x; 1.2810x over previous
//
#include <hip/hip_runtime.h>
#include <stdint.h>

// MultiHeadSelfAttention: B=2, T=2048, C=1024, H=16, Dk=64, fp32 in/out.
// R9: revert k_attn to R6 (dbuf LDS staging, 72.4us known — R8's direct
//     global fragments were uncoalesced, 64 txn/load). New: qkv V-third
//     through LDS transpose (b64 LDS writes, coalesced b128 global stores);
//     was 16 scattered 8B global stores/lane (4KB lane stride).

typedef __bf16 bf16;
typedef __bf16 bf16x8 __attribute__((ext_vector_type(8)));
typedef __bf16 bf16x4 __attribute__((ext_vector_type(4)));
typedef float  f32x4  __attribute__((ext_vector_type(4)));

#define SEQ_T 2048
#define CDIM 1024
#define BT   4096   // B*T

// async global->LDS, 16B per lane. LDS dest = wave-uniform base + lane*16.
__device__ __forceinline__ void gload16(const void* g, void* l) {
    __builtin_amdgcn_global_load_lds(
        (const __attribute__((address_space(1))) void*)(uintptr_t)g,
        (__attribute__((address_space(3))) void*)(uint32_t)(uintptr_t)l,
        16, 0, 0);
}

// ---------------------------------------------------------------- convert
__global__ __launch_bounds__(256) void k_convert(
    const float* __restrict__ x, const float* __restrict__ wqkv,
    const float* __restrict__ wout,
    bf16* __restrict__ xb, bf16* __restrict__ wqb, bf16* __restrict__ wob) {
    const int NX = (BT * CDIM) / 4;        // 1048576
    const int NQ = (3 * CDIM * CDIM) / 4;  // 786432
    const int NO = (CDIM * CDIM) / 4;      // 262144
    int i = blockIdx.x * 256 + threadIdx.x;
    const float4* src; bf16* dst; int j;
    if (i < NX)                    { src = (const float4*)x;    dst = xb;  j = i; }
    else if ((j = i - NX) < NQ)    { src = (const float4*)wqkv; dst = wqb; }
    else if ((j = i - NX - NQ) < NO) { src = (const float4*)wout; dst = wob; }
    else return;
    float4 v = src[j];
    bf16x4 o = { (bf16)v.x, (bf16)v.y, (bf16)v.z, (bf16)v.w };
    ((bf16x4*)dst)[j] = o;
}

// ------------------------------------------------------------- GEMM core
template <int BM, int BN, int MI, int NI>
__device__ __forceinline__ void gemm_core(
    const bf16* __restrict__ A, const bf16* __restrict__ Bw,
    bf16* As, bf16* Bs, int m0, int n0, int tid, f32x4 (&acc)[MI][NI]) {
    const int lane = tid & 63, wv = tid >> 6;
    const int quad = lane >> 4, lo = lane & 15;
    const int wm = (wv >> 1) * MI * 16, wn = (wv & 1) * NI * 16;
#pragma unroll
    for (int mi = 0; mi < MI; ++mi)
#pragma unroll
        for (int ni = 0; ni < NI; ++ni) acc[mi][ni] = 0.0f;

    for (int kk = 0; kk < 1024; kk += 32) {
        __syncthreads();
#pragma unroll
        for (int c = 0; c < BM / 64; ++c) {
            int slot = c * 256 + tid;
            int row = slot >> 2, sc = slot & 3;
            int g = sc ^ ((row >> 1) & 3);
            gload16(A + (m0 + row) * 1024 + kk + g * 8,
                    As + c * 2048 + (tid & 192) * 8);
        }
#pragma unroll
        for (int c = 0; c < BN / 64; ++c) {
            int slot = c * 256 + tid;
            int row = slot >> 2, sc = slot & 3;
            int g = sc ^ ((row >> 1) & 3);
            gload16(Bw + (n0 + row) * 1024 + kk + g * 8,
                    Bs + c * 2048 + (tid & 192) * 8);
        }
        __syncthreads();
        bf16x8 af[MI], bb[NI];
#pragma unroll
        for (int mi = 0; mi < MI; ++mi) {
            int row = wm + mi * 16 + lo;
            int ch = quad ^ ((row >> 1) & 3);
            af[mi] = *(const bf16x8*)(As + row * 32 + ch * 8);
        }
#pragma unroll
        for (int ni = 0; ni < NI; ++ni) {
            int row = wn + ni * 16 + lo;
            int ch = quad ^ ((row >> 1) & 3);
            bb[ni] = *(const bf16x8*)(Bs + row * 32 + ch * 8);
        }
#pragma unroll
        for (int mi = 0; mi < MI; ++mi)
#pragma unroll
            for (int ni = 0; ni < NI; ++ni)
                acc[mi][ni] = __builtin_amdgcn_mfma_f32_16x16x32_bf16(
                    af[mi], bb[ni], acc[mi][ni], 0, 0, 0);
    }
}

// ------------------------------------------------------------- QKV GEMM
// Q/K: C-tile transposed through LDS -> coalesced b128 stores to [b,h,t,d].
// V: C-tile transposed through LDS (n-half passes, b64 LDS writes since m
//    is the packed dim) -> coalesced b128 stores to vt[b,h,d,t].
__global__ __launch_bounds__(256) void k_gemm_qkv(
    const bf16* __restrict__ A, const bf16* __restrict__ Bw,
    const float* __restrict__ bias,
    bf16* __restrict__ qb, bf16* __restrict__ kb, bf16* __restrict__ vt) {
    __shared__ __align__(16) char pool[18432];   // As 8K | Bs 8K ; reused as T
    bf16* As = (bf16*)pool;
    bf16* Bs = (bf16*)(pool + 8192);
    bf16* T  = (bf16*)pool;                      // [64][136] = 17408 B
    const int tid = threadIdx.x;
    const int m0 = blockIdx.y * 128, n0 = blockIdx.x * 128;
    f32x4 acc[4][4];
    gemm_core<128, 128, 4, 4>(A, Bw, As, Bs, m0, n0, tid, acc);
    const int lane = tid & 63, wv = tid >> 6;
    const int quad = lane >> 4, lo = lane & 15;
    const int wm = (wv >> 1) * 64, wn = (wv & 1) * 64;
    const int which = n0 >> 10;
    if (which == 2) {
        // V transposed: two n-half passes. Owner waves (wn/64==p) write
        // T[n_local][m] with b64 (m packed per lane); all read out rows
        // n -> m(t)-contiguous -> coalesced 16B stores to vt[b,h,d,t].
        const int b = m0 >> 11, tt0 = m0 & 2047;
#pragma unroll
        for (int p = 0; p < 2; ++p) {
            __syncthreads();
            if ((wv & 1) == p) {
#pragma unroll
                for (int ni = 0; ni < 4; ++ni) {
                    int nl = ni * 16 + lo;
                    float bv = bias[n0 + wn + nl];
#pragma unroll
                    for (int mi = 0; mi < 4; ++mi) {
                        bf16x4 v4;
#pragma unroll
                        for (int r = 0; r < 4; ++r)
                            v4[r] = (bf16)(acc[mi][ni][r] + bv);
                        *(bf16x4*)(T + nl * 136 + wm + mi * 16 + quad * 4) = v4;
                    }
                }
            }
            __syncthreads();
#pragma unroll
            for (int pass = 0; pass < 4; ++pass) {
                int chunk = pass * 256 + tid;
                int nl = chunk >> 4, mc = chunk & 15;
                bf16x8 v = *(const bf16x8*)(T + nl * 136 + mc * 8);
                int n_g = n0 + p * 64 + nl;
                int h = (n_g >> 6) & 15, d = n_g & 63;
                *(bf16x8*)(vt + ((size_t)(b * 16 + h) * 64 + d) * 2048 +
                           tt0 + mc * 8) = v;
            }
        }
    } else {
        bf16* dst = which == 0 ? qb : kb;
        const float scale = which == 0 ? 0.125f * 1.44269504089f : 1.0f;
        // two m-half passes through LDS transpose buffer
#pragma unroll
        for (int p = 0; p < 2; ++p) {
            __syncthreads();
            if ((wv >> 1) == p) {   // waves holding m-rows [p*64, p*64+64)
#pragma unroll
                for (int ni = 0; ni < 4; ++ni) {
                    int n = wn + ni * 16 + lo;
                    float bv = bias[n0 + n];
#pragma unroll
                    for (int mi = 0; mi < 4; ++mi) {
#pragma unroll
                        for (int r = 0; r < 4; ++r) {
                            int ml = mi * 16 + quad * 4 + r;
                            T[ml * 136 + n] =
                                (bf16)((acc[mi][ni][r] + bv) * scale);
                        }
                    }
                }
            }
            __syncthreads();
#pragma unroll
            for (int pass = 0; pass < 4; ++pass) {
                int chunk = pass * 256 + tid;
                int ml = chunk >> 4, nc = chunk & 15;
                bf16x8 v = *(const bf16x8*)(T + ml * 136 + nc * 8);
                int n_g = n0 + nc * 8;
                int h = (n_g >> 6) & 15, d = n_g & 63;
                int t = m0 + p * 64 + ml;
                int b = t >> 11, tt = t & 2047;
                *(bf16x8*)(dst + ((size_t)(b * 16 + h) * 2048 + tt) * 64 + d) = v;
            }
        }
    }
}

// ------------------------------------------------------------ out-proj GEMM
__global__ __launch_bounds__(256) void k_gemm_out(
    const bf16* __restrict__ A, const bf16* __restrict__ Bw,
    const float* __restrict__ bias, float* __restrict__ out) {
    __shared__ __align__(16) bf16 As[128 * 32];
    __shared__ __align__(16) bf16 Bs[64 * 32];
    const int tid = threadIdx.x;
    const int m0 = blockIdx.y * 128, n0 = blockIdx.x * 64;
    f32x4 acc[4][2];
    gemm_core<128, 64, 4, 2>(A, Bw, As, Bs, m0, n0, tid, acc);
    const int lane = tid & 63, wv = tid >> 6;
    const int quad = lane >> 4, lo = lane & 15;
    const int wm = (wv >> 1) * 64, wn = (wv & 1) * 32;
#pragma unroll
    for (int ni = 0; ni < 2; ++ni) {
        int n = n0 + wn + ni * 16 + lo;
        float bv = bias[n];
#pragma unroll
        for (int mi = 0; mi < 4; ++mi) {
#pragma unroll
            for (int r = 0; r < 4; ++r) {
                int m = m0 + wm + mi * 16 + quad * 4 + r;
                out[(size_t)m * 1024 + n] = acc[mi][ni][r] + bv;
            }
        }
    }
}

// ---------------------------------------------------------- flash attention
// R9 = R6: S^T formulation, Q in registers, double-buffered K/V staging.
// LDS: Ks 2x8K + Vs 2x8K + Ps 18K = 50KB. Grid 512 (2 blocks/CU).
__global__ __launch_bounds__(256, 2) void k_attn(
    const bf16* __restrict__ qg, const bf16* __restrict__ kg,
    const bf16* __restrict__ vtg, bf16* __restrict__ og) {
    __shared__ __align__(16) bf16 Ks[2][64 * 64];
    __shared__ __align__(16) bf16 Vs[2][64 * 64];  // [d][s]
    __shared__ __align__(16) bf16 Ps[4][32 * 72];  // per-wave [q][s], +8 pad
    const int tid = threadIdx.x, lane = tid & 63, wv = tid >> 6;
    const int quad = lane >> 4, lo = lane & 15;
    const int bh = blockIdx.y, q0 = blockIdx.x * 128;
    const bf16* Qb = qg + (size_t)bh * 2048 * 64;
    const bf16* Kb = kg + (size_t)bh * 2048 * 64;
    const bf16* Vb = vtg + (size_t)bh * 64 * 2048;
    bf16* PsW = &Ps[wv][0];

    // staging lane->address terms (hoisted)
    const int srow = tid >> 3, ssc = tid & 7;
    const int sg0 = ssc ^ (srow & 7);
    const int srow1 = (256 + tid) >> 3;
    const int sg1 = ssc ^ (srow1 & 7);
    const int sbase = (tid & 192) * 8;

    // Q B-fragments: loop-invariant, straight from global into 16 VGPRs.
    bf16x8 bq[2][2];
#pragma unroll
    for (int nb = 0; nb < 2; ++nb)
#pragma unroll
        for (int ks = 0; ks < 2; ++ks)
            bq[nb][ks] = *(const bf16x8*)(
                Qb + (size_t)(q0 + wv * 32 + nb * 16 + lo) * 64 + ks * 32 + quad * 8);

    bf16x8 ones;
#pragma unroll
    for (int j = 0; j < 8; ++j) ones[j] = (bf16)1.0f;

    f32x4 oaccT[4][2];  // O^T: [d-block][q-block], col=q=lo, row=d=quad*4+r
    f32x4 osum[2];      // denominator, col=q=lo
#pragma unroll
    for (int db = 0; db < 4; ++db)
#pragma unroll
        for (int nb = 0; nb < 2; ++nb) oaccT[db][nb] = 0.0f;
    osum[0] = 0.0f; osum[1] = 0.0f;

    // prefetch tile 0 into buf 0
    gload16(Kb + srow * 64 + sg0 * 8, &Ks[0][0] + sbase);
    gload16(Kb + srow1 * 64 + sg1 * 8, &Ks[0][0] + 2048 + sbase);
    gload16(Vb + (size_t)srow * 2048 + sg0 * 8, &Vs[0][0] + sbase);
    gload16(Vb + (size_t)srow1 * 2048 + sg1 * 8, &Vs[0][0] + 2048 + sbase);

    for (int i = 0; i < SEQ_T / 64; ++i) {
        const int buf = i & 1;
        __syncthreads();  // prev reads of buf^1 done + vmcnt drain of DMA_i
        if (i + 1 < SEQ_T / 64) {
            const bf16* Kn = Kb + (i + 1) * 64 * 64;
            const bf16* Vn = Vb + (i + 1) * 64;
            bf16* KsN = &Ks[buf ^ 1][0];
            bf16* VsN = &Vs[buf ^ 1][0];
            gload16(Kn + srow * 64 + sg0 * 8, KsN + sbase);
            gload16(Kn + srow1 * 64 + sg1 * 8, KsN + 2048 + sbase);
            gload16(Vn + (size_t)srow * 2048 + sg0 * 8, VsN + sbase);
            gload16(Vn + (size_t)srow1 * 2048 + sg1 * 8, VsN + 2048 + sbase);
        }
        const bf16* KsB = &Ks[buf][0];
        const bf16* VsB = &Vs[buf][0];

        // S^T = K*Q^T: keys [0,64) x wave's q-rows [wv*32, +32)
        f32x4 sacc[4][2];
#pragma unroll
        for (int sb = 0; sb < 4; ++sb)
#pragma unroll
            for (int nb = 0; nb < 2; ++nb) sacc[sb][nb] = 0.0f;
#pragma unroll
        for (int ks = 0; ks < 2; ++ks) {
            int c = ks * 4 + quad;
            bf16x8 ak[4];
#pragma unroll
            for (int sb = 0; sb < 4; ++sb) {
                int row = sb * 16 + lo;
                ak[sb] = *(const bf16x8*)(KsB + row * 64 + ((c ^ (row & 7)) * 8));
            }
#pragma unroll
            for (int sb = 0; sb < 4; ++sb)
#pragma unroll
                for (int nb = 0; nb < 2; ++nb)
                    sacc[sb][nb] = __builtin_amdgcn_mfma_f32_16x16x32_bf16(
                        ak[sb], bq[nb][ks], sacc[sb][nb], 0, 0, 0);
        }

        // P^T = exp2(S^T) -> Ps[q][s]: 4 consecutive s per lane, b64 write
#pragma unroll
        for (int sb = 0; sb < 4; ++sb) {
#pragma unroll
            for (int nb = 0; nb < 2; ++nb) {
                bf16x4 p4;
#pragma unroll
                for (int r = 0; r < 4; ++r) p4[r] = (bf16)exp2f(sacc[sb][nb][r]);
                *(bf16x4*)(PsW + (nb * 16 + lo) * 72 + sb * 16 + quad * 4) = p4;
            }
        }

        // O^T += V^T * P^T ; denom += ones * P^T (same-wave LDS, no barrier)
#pragma unroll
        for (int ks2 = 0; ks2 < 2; ++ks2) {
            bf16x8 bp[2], av[4];
#pragma unroll
            for (int nb = 0; nb < 2; ++nb)
                bp[nb] = *(const bf16x8*)(PsW + (nb * 16 + lo) * 72 + ks2 * 32 + quad * 8);
#pragma unroll
            for (int db = 0; db < 4; ++db) {
                int row = db * 16 + lo;
                av[db] = *(const bf16x8*)(VsB + row * 64 + (((ks2 * 4 + quad) ^ (row & 7)) * 8));
            }
#pragma unroll
            for (int nb = 0; nb < 2; ++nb)
                osum[nb] = __builtin_amdgcn_mfma_f32_16x16x32_bf16(
                    ones, bp[nb], osum[nb], 0, 0, 0);
#pragma unroll
            for (int db = 0; db < 4; ++db)
#pragma unroll
                for (int nb = 0; nb < 2; ++nb)
                    oaccT[db][nb] = __builtin_amdgcn_mfma_f32_16x16x32_bf16(
                        av[db], bp[nb], oaccT[db][nb], 0, 0, 0);
        }
    }

    // epilogue: O^T/denom -> attn_out [b, t, h*64+d]; packed 8B stores.
    const int b = bh >> 4, h = bh & 15;
#pragma unroll
    for (int nb = 0; nb < 2; ++nb) {
        float inv = 1.0f / osum[nb][0];
        int t = q0 + wv * 32 + nb * 16 + lo;
#pragma unroll
        for (int db = 0; db < 4; ++db) {
            bf16x4 o4;
#pragma unroll
            for (int r = 0; r < 4; ++r) o4[r] = (bf16)(oaccT[db][nb][r] * inv);
            *(bf16x4*)(og + ((size_t)b * 2048 + t) * 1024 + h * 64 + db * 16 + quad * 4) = o4;
        }
    }
}

// ---------------------------------------------------------------- launcher
extern "C" void kernel_launch(void* const* d_in, const int* in_sizes, int n_in,
                              void* d_out, int out_size, void* d_ws, size_t ws_size,
                              hipStream_t stream) {
    const float* x     = (const float*)d_in[0];
    const float* qkv_w = (const float*)d_in[1];
    const float* qkv_b = (const float*)d_in[2];
    const float* out_w = (const float*)d_in[3];
    const float* out_b = (const float*)d_in[4];
    float* out = (float*)d_out;
    char* ws = (char*)d_ws;
    // ws layout (48 MB total)
    bf16* xb  = (bf16*)(ws);                       // 8 MB  [4096][1024]
    bf16* wqb = (bf16*)(ws + 8388608);             // 6 MB  [3072][1024]
    bf16* wob = (bf16*)(ws + 14680064);            // 2 MB  [1024][1024]
    bf16* qb  = (bf16*)(ws + 16777216);            // 8 MB  [b,h,t,d]
    bf16* kb  = (bf16*)(ws + 25165824);            // 8 MB  [b,h,t,d]
    bf16* vt  = (bf16*)(ws + 33554432);            // 8 MB  [b,h,d,t]
    bf16* ao  = (bf16*)(ws + 41943040);            // 8 MB  [4096][1024]

    k_convert<<<8192, 256, 0, stream>>>(x, qkv_w, out_w, xb, wqb, wob);
    k_gemm_qkv<<<dim3(24, 32), 256, 0, stream>>>(xb, wqb, qkv_b, qb, kb, vt);
    k_attn<<<dim3(16, 32), 256, 0, stream>>>(qb, kb, vt, ao);
    k_gemm_out<<<dim3(16, 32), 256, 0, stream>>>(ao, wob, out_b, out);
}